// Round 1
// baseline (413.959 us; speedup 1.0000x reference)
//
#include <hip/hip_runtime.h>
#include <math.h>

#define B_ 32
#define T_ 1024
#define D_ 512
#define U_ 64
#define TS_ 2          // t-reduction split in K1
#define TH_ (T_/TS_)   // 512
#define TC_ 64         // K1 t-chunk staged in LDS
#define SR_ 10.0f
#define EPS_ 1e-7f

// ---------------------------------------------------------------------------
// K1: partial G matrices.  For each (b, d-tile of 64, t-half):
//   P[ts][b][m][d][u] += sum_{t in half} x?[b,t,d] * w?[t,u]
// mats: m0 = x1^T w2, m1 = x1^T w3, m2 = x2^T w2, m3 = x2^T w3
// ---------------------------------------------------------------------------
__global__ __launch_bounds__(256) void k1_partials(
    const float* __restrict__ x1, const float* __restrict__ x2,
    const float* __restrict__ w2, const float* __restrict__ w3,
    float* __restrict__ P)
{
    __shared__ float x1s[TC_*64];
    __shared__ float x2s[TC_*64];
    __shared__ float w2s[TC_*64];
    __shared__ float w3s[TC_*64];

    const int dt  = blockIdx.x;       // 0..7
    const int ts  = blockIdx.y;       // 0..TS_-1
    const int b   = blockIdx.z;       // 0..31
    const int d0  = dt * 64;
    const int tid = threadIdx.x;
    const int td  = tid & 15;         // d-group: d = d0 + td*4 + i
    const int tu  = tid >> 4;         // u-group: u = tu*4 + j

    float acc[4][4][4];
    #pragma unroll
    for (int m = 0; m < 4; ++m)
        #pragma unroll
        for (int i = 0; i < 4; ++i)
            #pragma unroll
            for (int j = 0; j < 4; ++j) acc[m][i][j] = 0.f;

    const size_t xb = (size_t)b * T_ * D_;

    for (int c = 0; c < TH_/TC_; ++c) {
        const int tb = ts*TH_ + c*TC_;
        #pragma unroll
        for (int j = 0; j < 4; ++j) {
            int l  = j*256 + tid;           // 0..1023
            int tl = l >> 4;                // 0..63
            int f  = (l & 15) << 2;         // 0..60
            *(float4*)&x1s[tl*64 + f] = *(const float4*)&x1[xb + (size_t)(tb+tl)*D_ + d0 + f];
            *(float4*)&x2s[tl*64 + f] = *(const float4*)&x2[xb + (size_t)(tb+tl)*D_ + d0 + f];
            *(float4*)&w2s[tl*64 + f] = *(const float4*)&w2[(size_t)(tb+tl)*U_ + f];
            *(float4*)&w3s[tl*64 + f] = *(const float4*)&w3[(size_t)(tb+tl)*U_ + f];
        }
        __syncthreads();
        #pragma unroll 2
        for (int t = 0; t < TC_; ++t) {
            float4 a1 = *(const float4*)&x1s[t*64 + td*4];
            float4 a2 = *(const float4*)&x2s[t*64 + td*4];
            float4 c2 = *(const float4*)&w2s[t*64 + tu*4];
            float4 c3 = *(const float4*)&w3s[t*64 + tu*4];
            float a1v[4] = {a1.x,a1.y,a1.z,a1.w};
            float a2v[4] = {a2.x,a2.y,a2.z,a2.w};
            float c2v[4] = {c2.x,c2.y,c2.z,c2.w};
            float c3v[4] = {c3.x,c3.y,c3.z,c3.w};
            #pragma unroll
            for (int i = 0; i < 4; ++i)
                #pragma unroll
                for (int j = 0; j < 4; ++j) {
                    acc[0][i][j] += a1v[i]*c2v[j];
                    acc[1][i][j] += a1v[i]*c3v[j];
                    acc[2][i][j] += a2v[i]*c2v[j];
                    acc[3][i][j] += a2v[i]*c3v[j];
                }
        }
        __syncthreads();
    }

    #pragma unroll
    for (int m = 0; m < 4; ++m)
        #pragma unroll
        for (int i = 0; i < 4; ++i) {
            size_t idx = ((((size_t)ts*B_ + b)*4 + m)*D_ + (size_t)(d0 + td*4 + i))*U_ + tu*4;
            float4 v = {acc[m][i][0], acc[m][i][1], acc[m][i][2], acc[m][i][3]};
            *(float4*)&P[idx] = v;
        }
}

// ---------------------------------------------------------------------------
// K1b: M1 = w1 + (x2^T w2) + (x1^T w3) = w1 + m2 + m1
//      M2 = w1 + (x1^T w2) + (x2^T w3) = w1 + m0 + m3   (sum both t-halves)
// ---------------------------------------------------------------------------
__global__ __launch_bounds__(256) void k1_combine(
    const float* __restrict__ P, const float* __restrict__ w1,
    float* __restrict__ M1, float* __restrict__ M2)
{
    const int n = blockIdx.x*256 + threadIdx.x;   // 0 .. B*D*U/4-1
    const int b = n >> 13;                        // D*U/4 = 8192
    const int r = n & 8191;
    const size_t du = (size_t)r * 4;
    const size_t DU = (size_t)D_ * U_;
    float4 w = *(const float4*)&w1[du];
    const float* P0 = P + ((size_t)0*B_ + b)*4*DU + du;
    const float* P1 = P + ((size_t)1*B_ + b)*4*DU + du;
    float4 m0a = *(const float4*)&P0[0*DU], m0b = *(const float4*)&P1[0*DU];
    float4 m1a = *(const float4*)&P0[1*DU], m1b = *(const float4*)&P1[1*DU];
    float4 m2a = *(const float4*)&P0[2*DU], m2b = *(const float4*)&P1[2*DU];
    float4 m3a = *(const float4*)&P0[3*DU], m3b = *(const float4*)&P1[3*DU];
    float4 r1, r2;
    r1.x = w.x + m2a.x + m2b.x + m1a.x + m1b.x;
    r1.y = w.y + m2a.y + m2b.y + m1a.y + m1b.y;
    r1.z = w.z + m2a.z + m2b.z + m1a.z + m1b.z;
    r1.w = w.w + m2a.w + m2b.w + m1a.w + m1b.w;
    r2.x = w.x + m0a.x + m0b.x + m3a.x + m3b.x;
    r2.y = w.y + m0a.y + m0b.y + m3a.y + m3b.y;
    r2.z = w.z + m0a.z + m0b.z + m3a.z + m3b.z;
    r2.w = w.w + m0a.w + m0b.w + m3a.w + m3b.w;
    *(float4*)&M1[(size_t)b*DU + du] = r1;
    *(float4*)&M2[(size_t)b*DU + du] = r2;
}

// ---------------------------------------------------------------------------
// K2: eij[br][b][t] = SR * sum_u tanh( sum_d x[b,t,d]*M[b,d,u] ) * we[u]
// block: (t-tile 128) x (b) x (branch); 256 threads
// ---------------------------------------------------------------------------
#define TT_ 128
#define XPAD_ 132
__global__ __launch_bounds__(256) void k2_eij(
    const float* __restrict__ x1, const float* __restrict__ x2,
    const float* __restrict__ M1, const float* __restrict__ M2,
    const float* __restrict__ we, float* __restrict__ eij)
{
    __shared__ float xT[64*XPAD_];   // [d][t] transposed, padded
    __shared__ float Ms[64*64];      // [d][u]
    __shared__ float wes[64];
    __shared__ float red[8*TT_];

    const int tt = blockIdx.x;       // 0..7
    const int b  = blockIdx.y;       // 0..31
    const int br = blockIdx.z;       // 0..1
    const float* x = br ? x2 : x1;
    const float* M = (br ? M2 : M1) + (size_t)b * D_ * U_;
    const int tid = threadIdx.x;
    const int tdl = tid & 31;        // t = tdl*4 + i
    const int tu  = tid >> 5;        // u = tu*8 + j
    if (tid < 64) wes[tid] = we[tid];

    float acc[4][8];
    #pragma unroll
    for (int i = 0; i < 4; ++i)
        #pragma unroll
        for (int j = 0; j < 8; ++j) acc[i][j] = 0.f;

    const size_t xb = (size_t)b*T_*D_ + (size_t)tt*TT_*D_;

    for (int c = 0; c < D_/64; ++c) {
        #pragma unroll
        for (int j = 0; j < 8; ++j) {
            int l  = j*256 + tid;        // 0..2047
            int tl = l >> 4;             // 0..127
            int f  = (l & 15) << 2;      // 0..60
            float4 v = *(const float4*)&x[xb + (size_t)tl*D_ + c*64 + f];
            xT[(f+0)*XPAD_ + tl] = v.x;
            xT[(f+1)*XPAD_ + tl] = v.y;
            xT[(f+2)*XPAD_ + tl] = v.z;
            xT[(f+3)*XPAD_ + tl] = v.w;
        }
        #pragma unroll
        for (int j = 0; j < 4; ++j) {
            int l  = j*256 + tid;
            int dl = l >> 4;
            int f  = (l & 15) << 2;
            *(float4*)&Ms[dl*64 + f] = *(const float4*)&M[(size_t)(c*64 + dl)*U_ + f];
        }
        __syncthreads();
        #pragma unroll 2
        for (int d = 0; d < 64; ++d) {
            float4 xv = *(const float4*)&xT[d*XPAD_ + tdl*4];
            float4 mA = *(const float4*)&Ms[d*64 + tu*8];
            float4 mB = *(const float4*)&Ms[d*64 + tu*8 + 4];
            float xvv[4] = {xv.x,xv.y,xv.z,xv.w};
            float mv[8]  = {mA.x,mA.y,mA.z,mA.w,mB.x,mB.y,mB.z,mB.w};
            #pragma unroll
            for (int i = 0; i < 4; ++i)
                #pragma unroll
                for (int j = 0; j < 8; ++j)
                    acc[i][j] += xvv[i]*mv[j];
        }
        __syncthreads();
    }

    #pragma unroll
    for (int i = 0; i < 4; ++i) {
        float p = 0.f;
        #pragma unroll
        for (int j = 0; j < 8; ++j)
            p += tanhf(acc[i][j]) * wes[tu*8 + j];
        red[tu*TT_ + tdl*4 + i] = p;
    }
    __syncthreads();
    if (tid < TT_) {
        float s = 0.f;
        #pragma unroll
        for (int q = 0; q < 8; ++q) s += red[q*TT_ + tid];
        eij[((size_t)br*B_ + b)*T_ + tt*TT_ + tid] = SR_ * s;
    }
}

// ---------------------------------------------------------------------------
// K3: stable softmax over T per (branch,b): ww = exp(e-m)/(sum + eps*exp(-m))
// ---------------------------------------------------------------------------
__global__ __launch_bounds__(256) void k3_softmax(
    const float* __restrict__ eij, float* __restrict__ ww)
{
    __shared__ float sdata[256];
    const int bb  = blockIdx.x;                  // br*B + b, 0..63
    const int tid = threadIdx.x;
    const float* e = eij + (size_t)bb * T_;
    float v[4];
    float m = -1e30f;
    #pragma unroll
    for (int i = 0; i < 4; ++i) { v[i] = e[tid + i*256]; m = fmaxf(m, v[i]); }
    sdata[tid] = m; __syncthreads();
    for (int s = 128; s > 0; s >>= 1) {
        if (tid < s) sdata[tid] = fmaxf(sdata[tid], sdata[tid+s]);
        __syncthreads();
    }
    m = sdata[0]; __syncthreads();
    float ssum = 0.f;
    #pragma unroll
    for (int i = 0; i < 4; ++i) { v[i] = expf(v[i] - m); ssum += v[i]; }
    sdata[tid] = ssum; __syncthreads();
    for (int s = 128; s > 0; s >>= 1) {
        if (tid < s) sdata[tid] += sdata[tid+s];
        __syncthreads();
    }
    float inv = 1.0f / (sdata[0] + EPS_ * expf(-m));
    #pragma unroll
    for (int i = 0; i < 4; ++i) ww[(size_t)bb*T_ + tid + i*256] = v[i] * inv;
}

// ---------------------------------------------------------------------------
// K4: out[br][b,t,d] = x[b,t,d] * ww[br][b][t]
// ---------------------------------------------------------------------------
__global__ __launch_bounds__(256) void k4_scale(
    const float* __restrict__ x1, const float* __restrict__ x2,
    const float* __restrict__ ww, float* __restrict__ out)
{
    const size_t NF4 = (size_t)2*B_*T_*D_/4;     // 8388608
    size_t n = (size_t)blockIdx.x*256 + threadIdx.x;
    const size_t stride = (size_t)gridDim.x*256;
    for (; n < NF4; n += stride) {
        const size_t br = n >> 22;               // / (B*T*D/4)
        const size_t r  = n & ((1u<<22) - 1);
        const size_t bt = r >> 7;                // / (D/4)
        const float* x = br ? x2 : x1;
        float w = ww[br*(size_t)(B_*T_) + bt];
        float4 v = ((const float4*)x)[r];
        float4 o = {v.x*w, v.y*w, v.z*w, v.w*w};
        ((float4*)out)[n] = o;
    }
}

// ---------------------------------------------------------------------------
extern "C" void kernel_launch(void* const* d_in, const int* in_sizes, int n_in,
                              void* d_out, int out_size, void* d_ws, size_t ws_size,
                              hipStream_t stream)
{
    const float* x1 = (const float*)d_in[0];
    const float* x2 = (const float*)d_in[1];
    const float* w1 = (const float*)d_in[2];
    const float* w2 = (const float*)d_in[3];
    const float* w3 = (const float*)d_in[4];
    const float* we = (const float*)d_in[5];
    float* out = (float*)d_out;
    float* ws  = (float*)d_ws;

    // workspace layout (floats)
    float* P   = ws;                       // TS_*B_*4*D_*U_ = 8,388,608
    float* M1  = P   + (size_t)TS_*B_*4*D_*U_;   // 1,048,576
    float* M2  = M1  + (size_t)B_*D_*U_;         // 1,048,576
    float* eij = M2  + (size_t)B_*D_*U_;         // 65,536
    float* wwb = eij + (size_t)2*B_*T_;          // 65,536

    k1_partials<<<dim3(8, TS_, B_), 256, 0, stream>>>(x1, x2, w2, w3, P);
    k1_combine <<<dim3((B_*D_*U_/4 + 255)/256), 256, 0, stream>>>(P, w1, M1, M2);
    k2_eij     <<<dim3(T_/TT_, B_, 2), 256, 0, stream>>>(x1, x2, M1, M2, we, eij);
    k3_softmax <<<dim3(2*B_), 256, 0, stream>>>(eij, wwb);
    k4_scale   <<<dim3(8192), 256, 0, stream>>>(x1, x2, wwb, out);
}